// Round 1
// baseline (269.319 us; speedup 1.0000x reference)
//
#include <hip/hip_runtime.h>
#include <hip/hip_bf16.h>

// out[m, i] = sum_{j<=i} X[m, j] * W[i, j] + b[i]
// => C = X @ tril(W)^T + b  :  M=65536, N=512, K=512, fp32 in/out.
// bf16 MFMA GEMM, 128x128 tile, BK=64, 4 waves (2x2), 4x4 16x16x32 frags/wave.
// Reg-staged fp32->bf16 conversion into XOR-swizzled LDS; tril mask applied
// during W staging; K-loop bounded by n0+BN (triangular skip).

#define TK 512
#define BM 128
#define BN 128
#define BK 64

typedef __attribute__((ext_vector_type(4))) float f32x4;
typedef __attribute__((ext_vector_type(8))) __bf16 bf16x8;

__global__ __launch_bounds__(256, 2)
void triu_gemm_kernel(const float* __restrict__ X, const float* __restrict__ W,
                      const float* __restrict__ bias, float* __restrict__ out) {
    const int bm = blockIdx.x * BM;          // M-tile base row
    const int n0 = blockIdx.y * BN;          // N-tile base col
    const int kmax = n0 + BN;                // triangular: cols < n0+BN need k <= n0+BN-1

    // LDS: [row][64] bf16, 128B row stride. Chunk = 8 bf16 (16B).
    // XOR swizzle: chunk' = chunk ^ (row & 7)  -> ds_read_b128 ~2-way (free).
    __shared__ __bf16 As[BM][BK];
    __shared__ __bf16 Bs[BN][BK];

    const int t    = threadIdx.x;
    const int wave = t >> 6;
    const int lane = t & 63;
    const int wr   = wave >> 1;      // wave row 0..1 (64 output rows each)
    const int wc   = wave & 1;       // wave col 0..1 (64 output cols each)
    const int l15  = lane & 15;
    const int l4   = lane >> 4;      // 0..3 -> k-subchunk

    // staging coords: 8 threads cover one 64-float row segment; 32 rows/pass
    const int srow   = t >> 3;       // 0..31
    const int schunk = t & 7;        // which 8-float chunk along K

    f32x4 acc[4][4];
    #pragma unroll
    for (int m = 0; m < 4; ++m)
        #pragma unroll
        for (int n = 0; n < 4; ++n)
            acc[m][n] = (f32x4){0.f, 0.f, 0.f, 0.f};

    for (int k0 = 0; k0 < kmax; k0 += BK) {
        __syncthreads();   // previous iteration's reads done before overwrite

        // ---- stage A: X[bm..bm+127][k0..k0+63] -> bf16 LDS ----
        #pragma unroll
        for (int i = 0; i < 4; ++i) {
            const int row = i * 32 + srow;
            const float* src = X + (size_t)(bm + row) * TK + k0 + schunk * 8;
            f32x4 v0 = *reinterpret_cast<const f32x4*>(src);
            f32x4 v1 = *reinterpret_cast<const f32x4*>(src + 4);
            bf16x8 p;
            p[0] = (__bf16)v0[0]; p[1] = (__bf16)v0[1];
            p[2] = (__bf16)v0[2]; p[3] = (__bf16)v0[3];
            p[4] = (__bf16)v1[0]; p[5] = (__bf16)v1[1];
            p[6] = (__bf16)v1[2]; p[7] = (__bf16)v1[3];
            const int wchunk = schunk ^ (row & 7);
            *reinterpret_cast<bf16x8*>(&As[row][wchunk * 8]) = p;
        }

        // ---- stage B: tril(W)[n0+row][k0..k0+63] -> bf16 LDS ----
        #pragma unroll
        for (int i = 0; i < 4; ++i) {
            const int row  = i * 32 + srow;     // local output col
            const int ncol = n0 + row;          // global output col
            const float* src = W + (size_t)ncol * TK + k0 + schunk * 8;
            f32x4 v0 = *reinterpret_cast<const f32x4*>(src);
            f32x4 v1 = *reinterpret_cast<const f32x4*>(src + 4);
            const int kbase = k0 + schunk * 8;
            bf16x8 p;
            #pragma unroll
            for (int e = 0; e < 4; ++e)
                p[e] = (kbase + e <= ncol) ? (__bf16)v0[e] : (__bf16)0.f;
            #pragma unroll
            for (int e = 0; e < 4; ++e)
                p[4 + e] = (kbase + 4 + e <= ncol) ? (__bf16)v1[e] : (__bf16)0.f;
            const int wchunk = schunk ^ (row & 7);
            *reinterpret_cast<bf16x8*>(&Bs[row][wchunk * 8]) = p;
        }

        __syncthreads();   // staging visible

        // ---- MFMA: 2 k-substeps of 32, 4x4 fragments ----
        #pragma unroll
        for (int ks = 0; ks < 2; ++ks) {
            bf16x8 a[4], bb[4];
            #pragma unroll
            for (int m = 0; m < 4; ++m) {
                const int row    = wr * 64 + m * 16 + l15;
                const int chunk  = ks * 4 + l4;
                const int rchunk = chunk ^ (row & 7);
                a[m] = *reinterpret_cast<const bf16x8*>(&As[row][rchunk * 8]);
            }
            #pragma unroll
            for (int n = 0; n < 4; ++n) {
                const int row    = wc * 64 + n * 16 + l15;
                const int chunk  = ks * 4 + l4;
                const int rchunk = chunk ^ (row & 7);
                bb[n] = *reinterpret_cast<const bf16x8*>(&Bs[row][rchunk * 8]);
            }
            #pragma unroll
            for (int m = 0; m < 4; ++m)
                #pragma unroll
                for (int n = 0; n < 4; ++n)
                    acc[m][n] = __builtin_amdgcn_mfma_f32_16x16x32_bf16(
                        a[m], bb[n], acc[m][n], 0, 0, 0);
        }
    }

    // ---- epilogue: C[row][col] = acc + bias[col] ----
    // C/D layout (verified m89): col = lane&15, row = (lane>>4)*4 + reg
    #pragma unroll
    for (int n = 0; n < 4; ++n) {
        const int col = n0 + wc * 64 + n * 16 + l15;
        const float bv = bias[col];
        #pragma unroll
        for (int m = 0; m < 4; ++m) {
            const int row0 = bm + wr * 64 + m * 16 + l4 * 4;
            #pragma unroll
            for (int j = 0; j < 4; ++j)
                out[(size_t)(row0 + j) * TK + col] = acc[m][n][j] + bv;
        }
    }
}

extern "C" void kernel_launch(void* const* d_in, const int* in_sizes, int n_in,
                              void* d_out, int out_size, void* d_ws, size_t ws_size,
                              hipStream_t stream) {
    const float* X = (const float*)d_in[0];
    const float* W = (const float*)d_in[1];
    const float* b = (const float*)d_in[2];
    float* out = (float*)d_out;

    const int M = in_sizes[0] / TK;          // 65536
    dim3 grid(M / BM, TK / BN);              // (512, 4)
    triu_gemm_kernel<<<grid, 256, 0, stream>>>(X, W, b, out);
}

// Round 2
// 264.844 us; speedup vs baseline: 1.0169x; 1.0169x over previous
//
#include <hip/hip_runtime.h>
#include <hip/hip_bf16.h>

// out[m, i] = sum_{j<=i} X[m, j] * W[i, j] + b[i]
// => C = X @ tril(W)^T + b  :  M=65536, N=512, K=512, fp32 in/out.
// bf16 MFMA GEMM, 128x128 tile, BK=64, 4 waves (2x2), 4x4 16x16x32 frags/wave.
// R2: T14 async-STAGE split — issue k+1 global loads (to regs) before the
// k-tile MFMA; cvt+ds_write after the post-compute barrier. Single LDS buffer,
// 2 barriers/K-step, HBM latency hidden under compute.

#define TK 512
#define BM 128
#define BN 128
#define BK 64

typedef __attribute__((ext_vector_type(4))) float f32x4;
typedef __attribute__((ext_vector_type(8))) __bf16 bf16x8;

__global__ __launch_bounds__(256, 2)
void triu_gemm_kernel(const float* __restrict__ X, const float* __restrict__ W,
                      const float* __restrict__ bias, float* __restrict__ out) {
    const int bm = blockIdx.x * BM;          // M-tile base row
    const int n0 = blockIdx.y * BN;          // N-tile base col
    const int kmax = n0 + BN;                // triangular skip

    // LDS: [row][64] bf16, 128B row stride, chunk(16B) XOR-swizzled by row&7.
    __shared__ __bf16 As[BM][BK];
    __shared__ __bf16 Bs[BN][BK];

    const int t    = threadIdx.x;
    const int wave = t >> 6;
    const int lane = t & 63;
    const int wr   = wave >> 1;
    const int wc   = wave & 1;
    const int l15  = lane & 15;
    const int l4   = lane >> 4;

    const int srow   = t >> 3;       // 0..31 (row within 32-row staging pass)
    const int schunk = t & 7;        // 8-float chunk along K

    f32x4 acc[4][4];
    #pragma unroll
    for (int m = 0; m < 4; ++m)
        #pragma unroll
        for (int n = 0; n < 4; ++n)
            acc[m][n] = (f32x4){0.f, 0.f, 0.f, 0.f};

    // prefetch registers: one K-tile of A and B (fp32), 32 floats each
    f32x4 pa[4][2], pb[4][2];

    auto issue_loads = [&](int k0) {
        #pragma unroll
        for (int i = 0; i < 4; ++i) {
            const int row = i * 32 + srow;
            const float* sa = X + (size_t)(bm + row) * TK + k0 + schunk * 8;
            pa[i][0] = *reinterpret_cast<const f32x4*>(sa);
            pa[i][1] = *reinterpret_cast<const f32x4*>(sa + 4);
            const float* sb = W + (size_t)(n0 + row) * TK + k0 + schunk * 8;
            pb[i][0] = *reinterpret_cast<const f32x4*>(sb);
            pb[i][1] = *reinterpret_cast<const f32x4*>(sb + 4);
        }
    };

    auto write_tiles = [&](int k0) {
        const int kbase = k0 + schunk * 8;
        #pragma unroll
        for (int i = 0; i < 4; ++i) {
            const int row    = i * 32 + srow;
            const int wchunk = schunk ^ (row & 7);
            bf16x8 p;
            #pragma unroll
            for (int e = 0; e < 4; ++e) p[e]     = (__bf16)pa[i][0][e];
            #pragma unroll
            for (int e = 0; e < 4; ++e) p[4 + e] = (__bf16)pa[i][1][e];
            *reinterpret_cast<bf16x8*>(&As[row][wchunk * 8]) = p;

            const int ncol = n0 + row;           // tril mask: k <= ncol
            bf16x8 q;
            #pragma unroll
            for (int e = 0; e < 4; ++e)
                q[e]     = (kbase + e     <= ncol) ? (__bf16)pb[i][0][e] : (__bf16)0.f;
            #pragma unroll
            for (int e = 0; e < 4; ++e)
                q[4 + e] = (kbase + 4 + e <= ncol) ? (__bf16)pb[i][1][e] : (__bf16)0.f;
            *reinterpret_cast<bf16x8*>(&Bs[row][wchunk * 8]) = q;
        }
    };

    // prologue: tile k=0
    issue_loads(0);
    write_tiles(0);
    __syncthreads();

    for (int k0 = 0; k0 < kmax; k0 += BK) {
        const int kn = k0 + BK;
        const bool has_next = kn < kmax;
        if (has_next) issue_loads(kn);   // in flight during MFMA below

        #pragma unroll
        for (int ks = 0; ks < 2; ++ks) {
            bf16x8 a[4], bb[4];
            #pragma unroll
            for (int m = 0; m < 4; ++m) {
                const int row    = wr * 64 + m * 16 + l15;
                const int rchunk = (ks * 4 + l4) ^ (row & 7);
                a[m] = *reinterpret_cast<const bf16x8*>(&As[row][rchunk * 8]);
            }
            #pragma unroll
            for (int n = 0; n < 4; ++n) {
                const int row    = wc * 64 + n * 16 + l15;
                const int rchunk = (ks * 4 + l4) ^ (row & 7);
                bb[n] = *reinterpret_cast<const bf16x8*>(&Bs[row][rchunk * 8]);
            }
            #pragma unroll
            for (int m = 0; m < 4; ++m)
                #pragma unroll
                for (int n = 0; n < 4; ++n)
                    acc[m][n] = __builtin_amdgcn_mfma_f32_16x16x32_bf16(
                        a[m], bb[n], acc[m][n], 0, 0, 0);
        }

        __syncthreads();                 // all LDS reads of tile k0 done
        if (has_next) write_tiles(kn);   // waits vmcnt, cvt, ds_write
        __syncthreads();                 // tile kn visible
    }

    // epilogue: C/D layout col = lane&15, row = (lane>>4)*4 + reg
    #pragma unroll
    for (int n = 0; n < 4; ++n) {
        const int col = n0 + wc * 64 + n * 16 + l15;
        const float bv = bias[col];
        #pragma unroll
        for (int m = 0; m < 4; ++m) {
            const int row0 = bm + wr * 64 + m * 16 + l4 * 4;
            #pragma unroll
            for (int j = 0; j < 4; ++j)
                out[(size_t)(row0 + j) * TK + col] = acc[m][n][j] + bv;
        }
    }
}

extern "C" void kernel_launch(void* const* d_in, const int* in_sizes, int n_in,
                              void* d_out, int out_size, void* d_ws, size_t ws_size,
                              hipStream_t stream) {
    const float* X = (const float*)d_in[0];
    const float* W = (const float*)d_in[1];
    const float* b = (const float*)d_in[2];
    float* out = (float*)d_out;

    const int M = in_sizes[0] / TK;          // 65536
    dim3 grid(M / BM, TK / BN);              // (512, 4)
    triu_gemm_kernel<<<grid, 256, 0, stream>>>(X, W, b, out);
}